// Round 5
// baseline (957.693 us; speedup 1.0000x reference)
//
#include <hip/hip_runtime.h>

#define ARTIST_V 16384
#define GENRE_V  2048
#define TOTAL    18433
#define HIDDEN   9216
#define OUT_D    64
#define BATCH    4096

// k_hidden geometry
#define ROWS_PB  8
#define NBLK     (HIDDEN / ROWS_PB)    // 1152 blocks
#define THR      512
#define SEG      (TOTAL - 1)           // 18432 staged columns (year col via SGPR)
#define PF_N     (SEG / 4 / THR)       // 9 float4 per thread per row

// k_gemm geometry
#define KSPLIT   8
#define KCHUNK   (HIDDEN / KSPLIT)     // 1152 (36 k-steps of 32)

typedef unsigned int   uint;
typedef unsigned short ushort;
typedef __attribute__((ext_vector_type(8))) short short8;
typedef __attribute__((ext_vector_type(4))) float f32x4;

__device__ __forceinline__ ushort f2bf(float f) {
    uint u = __float_as_uint(f);
    u += 0x7FFFu + ((u >> 16) & 1u);   // RNE
    return (ushort)(u >> 16);
}
__device__ __forceinline__ float bf2f(ushort b) {
    return __uint_as_float(((uint)b) << 16);
}
// HW packed convert: lo16 = bf16(a), hi16 = bf16(b)  [T12 recipe, RNE]
__device__ __forceinline__ uint cvt_pk(float a, float b) {
    uint r;
    asm("v_cvt_pk_bf16_f32 %0, %1, %2" : "=v"(r) : "v"(a), "v"(b));
    return r;
}

// ---------------------------------------------------------------------------
// W2 fp32 -> bf16 row-major [64][9216]  (576 blocks x 256 thr x 4 elems)
__global__ __launch_bounds__(256) void k_prep(const float* __restrict__ W2,
                                              ushort* __restrict__ W2b) {
    int t = blockIdx.x * 256 + threadIdx.x;       // 0..147455
    float4 v = *(const float4*)(W2 + (size_t)t * 4);
    uint2 p;
    p.x = cvt_pk(v.x, v.y);
    p.y = cvt_pk(v.z, v.w);
    *(uint2*)(W2b + (size_t)t * 4) = p;
}

// ---------------------------------------------------------------------------
// H2v[h/8][b] = uint4 of 8 bf16 = relu(W1[h,a_b] + W1[h,AV+g_b] + y_b*W1[h,last] + b1[h])
// Double-buffered LDS rows; ONE barrier per row; prefetch row r+1 during gather r.
__global__ __launch_bounds__(THR, 4) void k_hidden(
    const int*   __restrict__ artist,
    const int*   __restrict__ genre,
    const float* __restrict__ year,
    const float* __restrict__ W1,
    const float* __restrict__ b1,
    uint4*       __restrict__ H2v)
{
    __shared__ ushort srow[2][SEG];               // 2 x 36,864 B = 73,728 B -> 2 blocks/CU
    const int tid = threadIdx.x;
    const int hb  = blockIdx.x;
    const int h0  = hb * ROWS_PB;

    // hoist per-batch inputs (8 chunks of 512)
    uint  ag[8]; float yv[8];
    #pragma unroll
    for (int j = 0; j < 8; j++) {
        int b = tid + THR * j;
        ag[j] = (uint)artist[b] | ((uint)genre[b] << 16);
        yv[j] = year[b];
    }
    // uniform per-row constants -> SGPRs
    float ywA[ROWS_PB], b1A[ROWS_PB];
    #pragma unroll
    for (int r = 0; r < ROWS_PB; r++) {
        ywA[r] = W1[(size_t)(h0 + r) * TOTAL + SEG];
        b1A[r] = b1[h0 + r];
    }

    uint res[8][4];
    #pragma unroll
    for (int j = 0; j < 8; j++)
        { res[j][0] = 0u; res[j][1] = 0u; res[j][2] = 0u; res[j][3] = 0u; }

    float4 pf[PF_N];
    {   // stage row 0 into buffer 0
        const float4* vp = (const float4*)(W1 + (size_t)h0 * TOTAL);
        #pragma unroll
        for (int i = 0; i < PF_N; i++) pf[i] = vp[i * THR + tid];
        #pragma unroll
        for (int i = 0; i < PF_N; i++) {
            uint2 p; p.x = cvt_pk(pf[i].x, pf[i].y); p.y = cvt_pk(pf[i].z, pf[i].w);
            *(uint2*)(&srow[0][(i * THR + tid) * 4]) = p;
        }
        __syncthreads();
    }

    #pragma unroll
    for (int r = 0; r < ROWS_PB; r++) {
        if (r + 1 < ROWS_PB) {                    // issue next row's loads EARLY
            const float4* vp = (const float4*)(W1 + (size_t)(h0 + r + 1) * TOTAL);
            #pragma unroll
            for (int i = 0; i < PF_N; i++) pf[i] = vp[i * THR + tid];
        }
        const ushort* sr = srow[r & 1];
        const float yw = ywA[r], bh = b1A[r];
        #pragma unroll
        for (int j = 0; j < 8; j++) {             // gather row r (overlaps loads)
            int a = (int)(ag[j] & 0xFFFFu);
            int g = (int)(ag[j] >> 16);
            float hv = bf2f(sr[a]) + bf2f(sr[ARTIST_V + g]) + yv[j] * yw + bh;
            hv = fmaxf(hv, 0.0f);
            res[j][r >> 1] |= ((uint)f2bf(hv)) << ((r & 1) * 16);
        }
        if (r + 1 < ROWS_PB) {                    // convert + write row r+1 to OTHER buffer
            ushort* sw = srow[(r + 1) & 1];
            #pragma unroll
            for (int i = 0; i < PF_N; i++) {
                uint2 p; p.x = cvt_pk(pf[i].x, pf[i].y); p.y = cvt_pk(pf[i].z, pf[i].w);
                *(uint2*)(&sw[(i * THR + tid) * 4]) = p;
            }
            __syncthreads();                      // single barrier per row
        }
    }

    const size_t obase = (size_t)hb * BATCH;      // uint4 units
    #pragma unroll
    for (int j = 0; j < 8; j++) {
        uint4 v; v.x = res[j][0]; v.y = res[j][1]; v.z = res[j][2]; v.w = res[j][3];
        H2v[obase + tid + THR * j] = v;           // 16B/lane coalesced
    }
}

// ---------------------------------------------------------------------------
// part[split][b][o] = sum_{k in chunk} H[b][k] * W2[o][k]   (no atomics)
__global__ __launch_bounds__(256, 2) void k_gemm(
    const uint4*  __restrict__ H2v,
    const ushort* __restrict__ W2b,
    float*        __restrict__ part)
{
    const int lane = threadIdx.x & 63;
    const int wv   = threadIdx.x >> 6;
    const int l15  = lane & 15;
    const int lhi  = lane >> 4;
    const int m0   = blockIdx.x * 64 + wv * 16;
    const int k0   = blockIdx.y * KCHUNK;

    f32x4 acc[4];
    #pragma unroll
    for (int n = 0; n < 4; n++) acc[n] = (f32x4){0.f, 0.f, 0.f, 0.f};

    uint4 avn = H2v[(size_t)((k0 >> 3) + lhi) * BATCH + m0 + l15];   // A prefetch
    for (int kk = k0; kk < k0 + KCHUNK; kk += 32) {
        uint4 av = avn;
        if (kk + 32 < k0 + KCHUNK)
            avn = H2v[(size_t)(((kk + 32) >> 3) + lhi) * BATCH + m0 + l15];
        union { uint4 u; short8 s; } ua; ua.u = av;
        short8 afrag = ua.s;

        const ushort* wb = W2b + (size_t)l15 * HIDDEN + kk + lhi * 8;
        #pragma unroll
        for (int n = 0; n < 4; n++) {
            short8 bfrag = *(const short8*)(wb + (size_t)(n * 16) * HIDDEN);
            acc[n] = __builtin_amdgcn_mfma_f32_16x16x32_bf16(afrag, bfrag, acc[n], 0, 0, 0);
        }
    }

    float* pb = part + (size_t)blockIdx.y * (BATCH * OUT_D);
    #pragma unroll
    for (int n = 0; n < 4; n++) {
        #pragma unroll
        for (int r = 0; r < 4; r++)
            pb[(size_t)(m0 + lhi * 4 + r) * OUT_D + n * 16 + l15] = acc[n][r];
    }
}

// ---------------------------------------------------------------------------
// out[b][o] = b2[o] + sum_splits part[s][b][o]    (256 blocks x 256 thr, float4)
__global__ __launch_bounds__(256) void k_reduce(const float* __restrict__ part,
                                                const float* __restrict__ b2,
                                                float4*      __restrict__ out4) {
    int idx = blockIdx.x * 256 + threadIdx.x;     // 0..65535 float4
    const float4* p = (const float4*)part;
    float4 bb = ((const float4*)b2)[threadIdx.x & 15];
    float4 o = bb;
    #pragma unroll
    for (int s = 0; s < KSPLIT; s++) {
        float4 v = p[idx + (size_t)s * 65536];
        o.x += v.x; o.y += v.y; o.z += v.z; o.w += v.w;
    }
    out4[idx] = o;
}

// ---------------------------------------------------------------------------
extern "C" void kernel_launch(void* const* d_in, const int* in_sizes, int n_in,
                              void* d_out, int out_size, void* d_ws, size_t ws_size,
                              hipStream_t stream) {
    const int*   artist = (const int*)d_in[0];
    const int*   genre  = (const int*)d_in[1];
    const float* year   = (const float*)d_in[2];
    const float* W1     = (const float*)d_in[3];
    const float* b1     = (const float*)d_in[4];
    const float* W2     = (const float*)d_in[5];
    const float* b2     = (const float*)d_in[6];
    float* out = (float*)d_out;

    char* ws = (char*)d_ws;
    uint4*  H2v  = (uint4*)ws;                                 // 75,497,472 B
    ushort* W2b  = (ushort*)(ws + 75497472);                   //  1,179,648 B
    float*  part = (float*)(ws + 75497472 + 1179648);          //  8,388,608 B

    k_prep  <<<576, 256, 0, stream>>>(W2, W2b);
    k_hidden<<<NBLK, THR, 0, stream>>>(artist, genre, year, W1, b1, H2v);
    k_gemm  <<<dim3(BATCH / 64, KSPLIT), 256, 0, stream>>>(H2v, W2b, part);
    k_reduce<<<256, 256, 0, stream>>>(part, b2, (float4*)out);
}

// Round 6
// 930.561 us; speedup vs baseline: 1.0292x; 1.0292x over previous
//
#include <hip/hip_runtime.h>

#define ARTIST_V 16384
#define GENRE_V  2048
#define TOTAL    18433
#define HIDDEN   9216
#define OUT_D    64
#define BATCH    4096

// k_hidden geometry: 256 blocks x 512 thr, 36 rows/block, fp32 LDS double-buffer
#define THR      512
#define RPB      36                    // rows per block = HIDDEN/256
#define SEG      18432                 // staged cols (year col via scalar load)

// k_gemm geometry
#define KSPLIT   8
#define KCHUNK   (HIDDEN / KSPLIT)     // 1152 (36 k-steps of 32)

typedef unsigned int   uint;
typedef unsigned short ushort;
typedef __attribute__((ext_vector_type(8))) short short8;
typedef __attribute__((ext_vector_type(4))) float f32x4;

// HW packed convert: lo16 = bf16(a), hi16 = bf16(b)
__device__ __forceinline__ uint cvt_pk(float a, float b) {
    uint r;
    asm("v_cvt_pk_bf16_f32 %0, %1, %2" : "=v"(r) : "v"(a), "v"(b));
    return r;
}

// async global->LDS DMA of one row-slice: this wave's 2304 floats (36 x 256B)
// g: per-lane global ptr (base + woff + lane), l: wave-uniform LDS ptr (base + woff)
__device__ __forceinline__ void dma_row(const float* __restrict__ g, float* l) {
    #pragma unroll
    for (int i = 0; i < 36; ++i)
        __builtin_amdgcn_global_load_lds(
            (const __attribute__((address_space(1))) void*)(g + i * 64),
            (__attribute__((address_space(3))) void*)(l + i * 64), 4, 0, 0);
}

// ---------------------------------------------------------------------------
// W2 fp32 -> bf16 row-major [64][9216]  (576 blocks x 256 thr x 4 elems)
__global__ __launch_bounds__(256) void k_prep(const float* __restrict__ W2,
                                              ushort* __restrict__ W2b) {
    int t = blockIdx.x * 256 + threadIdx.x;       // 0..147455
    float4 v = *(const float4*)(W2 + (size_t)t * 4);
    uint2 p;
    p.x = cvt_pk(v.x, v.y);
    p.y = cvt_pk(v.z, v.w);
    *(uint2*)(W2b + (size_t)t * 4) = p;
}

// ---------------------------------------------------------------------------
// H2[h/4][b] = uint2 of 4 bf16 rows = relu(W1[h,a_b]+W1[h,AV+g_b]+y_b*W1[h,last]+b1[h])
// fp32 rows DMA'd straight to LDS; DMA(r+1) in flight during gather(r) + barrier.
__global__ __launch_bounds__(THR) void k_hidden(
    const int*   __restrict__ artist,
    const int*   __restrict__ genre,
    const float* __restrict__ year,
    const float* __restrict__ W1,
    const float* __restrict__ b1,
    uint2*       __restrict__ H2)
{
    __shared__ float sbuf[2][SEG];                // 147,456 B -> 1 block/CU
    const int tid  = threadIdx.x;
    const int w    = tid >> 6;
    const int ln   = tid & 63;
    const int woff = w * (SEG / 8);               // 2304 floats per wave slice
    const int r0   = blockIdx.x * RPB;

    // hoist per-batch inputs (8 chunks of 512)
    int aix[8], gix[8]; float yv[8];
    #pragma unroll
    for (int j = 0; j < 8; ++j) {
        int b = tid + THR * j;
        aix[j] = artist[b];
        gix[j] = ARTIST_V + genre[b];
        yv[j]  = year[b];
    }

    // prologue: row 0 -> buf 0
    dma_row(W1 + (size_t)r0 * TOTAL + woff + ln, &sbuf[0][woff]);
    __syncthreads();                              // drains DMA -> buf0 ready

    for (int m = 0; m < RPB / 4; ++m) {           // 9 macro-steps of 4 rows
        const int rb = 4 * m;
        const float4 bq = *(const float4*)(b1 + r0 + rb);   // uniform s_load
        float hvp[8];
        uint  pk0[8], pk1[8];
        #pragma unroll
        for (int s = 0; s < 4; ++s) {
            const int r = rb + s;                 // row parity == s&1 (rb % 4 == 0)
            if (r + 1 < RPB)                      // DMA next row into other buffer
                dma_row(W1 + (size_t)(r0 + r + 1) * TOTAL + woff + ln,
                        &sbuf[(s + 1) & 1][woff]);
            const float yw = W1[(size_t)(r0 + r) * TOTAL + SEG];   // year weight
            const float bh = (s == 0) ? bq.x : (s == 1) ? bq.y : (s == 2) ? bq.z : bq.w;
            const float* sb = sbuf[s & 1];
            #pragma unroll
            for (int j = 0; j < 8; ++j) {         // gather (overlaps DMA flight)
                float hv = sb[aix[j]] + sb[gix[j]] + fmaf(yv[j], yw, bh);
                hv = fmaxf(hv, 0.0f);
                if (s & 1) {
                    uint p = cvt_pk(hvp[j], hv);  // rows (r-1, r) packed
                    if (s == 1) pk0[j] = p; else pk1[j] = p;
                } else {
                    hvp[j] = hv;
                }
            }
            __syncthreads();                      // vmcnt(0): DMA(r+1) landed
        }
        const size_t qb = (size_t)(blockIdx.x * (RPB / 4) + m) * BATCH;
        #pragma unroll
        for (int j = 0; j < 8; ++j)               // 4 rows -> uint2, coalesced 8B/lane
            H2[qb + tid + THR * j] = make_uint2(pk0[j], pk1[j]);
    }
}

// ---------------------------------------------------------------------------
// part[split][b][o] = sum_{k in chunk} H[b][k] * W2[o][k]   (no atomics)
__global__ __launch_bounds__(256, 2) void k_gemm(
    const uint2*  __restrict__ H2,
    const ushort* __restrict__ W2b,
    float*        __restrict__ part)
{
    const int lane = threadIdx.x & 63;
    const int wv   = threadIdx.x >> 6;
    const int l15  = lane & 15;
    const int lhi  = lane >> 4;
    const int m0   = blockIdx.x * 64 + wv * 16;
    const int k0   = blockIdx.y * KCHUNK;

    f32x4 acc[4];
    #pragma unroll
    for (int n = 0; n < 4; n++) acc[n] = (f32x4){0.f, 0.f, 0.f, 0.f};

    int p = (k0 >> 2) + lhi * 2;                  // uint2-row of this lane's k-slice
    uint2 a0 = H2[(size_t)p * BATCH + m0 + l15];  // A prefetch
    uint2 a1 = H2[(size_t)(p + 1) * BATCH + m0 + l15];

    for (int kk = k0; kk < k0 + KCHUNK; kk += 32) {
        uint2 c0 = a0, c1 = a1;
        if (kk + 32 < k0 + KCHUNK) {
            int pn = ((kk + 32) >> 2) + lhi * 2;
            a0 = H2[(size_t)pn * BATCH + m0 + l15];
            a1 = H2[(size_t)(pn + 1) * BATCH + m0 + l15];
        }
        union { uint u[4]; short8 s; } ua;
        ua.u[0] = c0.x; ua.u[1] = c0.y; ua.u[2] = c1.x; ua.u[3] = c1.y;
        short8 afrag = ua.s;

        const ushort* wb = W2b + (size_t)l15 * HIDDEN + kk + lhi * 8;
        #pragma unroll
        for (int n = 0; n < 4; n++) {
            short8 bfrag = *(const short8*)(wb + (size_t)(n * 16) * HIDDEN);
            acc[n] = __builtin_amdgcn_mfma_f32_16x16x32_bf16(afrag, bfrag, acc[n], 0, 0, 0);
        }
    }

    float* pb = part + (size_t)blockIdx.y * (BATCH * OUT_D);
    #pragma unroll
    for (int n = 0; n < 4; n++) {
        #pragma unroll
        for (int r = 0; r < 4; r++)
            pb[(size_t)(m0 + lhi * 4 + r) * OUT_D + n * 16 + l15] = acc[n][r];
    }
}

// ---------------------------------------------------------------------------
// out[b][o] = b2[o] + sum_splits part[s][b][o]    (256 blocks x 256 thr, float4)
__global__ __launch_bounds__(256) void k_reduce(const float* __restrict__ part,
                                                const float* __restrict__ b2,
                                                float4*      __restrict__ out4) {
    int idx = blockIdx.x * 256 + threadIdx.x;     // 0..65535 float4
    const float4* p = (const float4*)part;
    float4 bb = ((const float4*)b2)[threadIdx.x & 15];
    float4 o = bb;
    #pragma unroll
    for (int s = 0; s < KSPLIT; s++) {
        float4 v = p[idx + (size_t)s * 65536];
        o.x += v.x; o.y += v.y; o.z += v.z; o.w += v.w;
    }
    out4[idx] = o;
}

// ---------------------------------------------------------------------------
extern "C" void kernel_launch(void* const* d_in, const int* in_sizes, int n_in,
                              void* d_out, int out_size, void* d_ws, size_t ws_size,
                              hipStream_t stream) {
    const int*   artist = (const int*)d_in[0];
    const int*   genre  = (const int*)d_in[1];
    const float* year   = (const float*)d_in[2];
    const float* W1     = (const float*)d_in[3];
    const float* b1     = (const float*)d_in[4];
    const float* W2     = (const float*)d_in[5];
    const float* b2     = (const float*)d_in[6];
    float* out = (float*)d_out;

    char* ws = (char*)d_ws;
    uint2*  H2   = (uint2*)ws;                                 // 2304*4096*8 = 75,497,472 B
    ushort* W2b  = (ushort*)(ws + 75497472);                   //  1,179,648 B
    float*  part = (float*)(ws + 75497472 + 1179648);          //  8,388,608 B

    k_prep  <<<576, 256, 0, stream>>>(W2, W2b);
    k_hidden<<<256, THR, 0, stream>>>(artist, genre, year, W1, b1, H2);
    k_gemm  <<<dim3(BATCH / 64, KSPLIT), 256, 0, stream>>>(H2, W2b, part);
    k_reduce<<<256, 256, 0, stream>>>(part, b2, (float4*)out);
}